// Round 1
// baseline (1046.438 us; speedup 1.0000x reference)
//
#include <hip/hip_runtime.h>
#include <hip/hip_bf16.h>

#define NN 8192
#define BM 128
#define BK 64

typedef __attribute__((ext_vector_type(8))) short          bf16x8;
typedef __attribute__((ext_vector_type(8))) unsigned short u16x8;
typedef __attribute__((ext_vector_type(4))) float          f32x4;

__device__ __forceinline__ unsigned short f2bf(float f) {
    unsigned int u = __builtin_bit_cast(unsigned int, f);
    u += 0x7fffu + ((u >> 16) & 1u);   // RNE; exact zeros stay zero
    return (unsigned short)(u >> 16);
}

// ---------------- fp32 -> bf16, same layout (A) ----------------
__global__ __launch_bounds__(256) void conv_a_kernel(const float* __restrict__ in,
                                                     unsigned short* __restrict__ out) {
    const size_t total = (size_t)NN * NN / 8;
    for (size_t i = (size_t)blockIdx.x * 256 + threadIdx.x; i < total;
         i += (size_t)gridDim.x * 256) {
        const f32x4 v0 = *(const f32x4*)(in + i * 8);
        const f32x4 v1 = *(const f32x4*)(in + i * 8 + 4);
        u16x8 o;
        o[0] = f2bf(v0[0]); o[1] = f2bf(v0[1]); o[2] = f2bf(v0[2]); o[3] = f2bf(v0[3]);
        o[4] = f2bf(v1[0]); o[5] = f2bf(v1[1]); o[6] = f2bf(v1[2]); o[7] = f2bf(v1[3]);
        *(u16x8*)(out + i * 8) = o;
    }
}

// ---------------- fp32 B[k][n] -> bf16 Bt[n][k] (transpose-convert) ----------------
__global__ __launch_bounds__(256) void conv_trans_b(const float* __restrict__ B,
                                                    unsigned short* __restrict__ Bt) {
    __shared__ unsigned short tile[64][66];   // pad 66: ~4-way worst on transposed read
    const int c0 = blockIdx.x * 64;   // n base
    const int r0 = blockIdx.y * 64;   // k base
    const int t  = threadIdx.x;
    #pragma unroll
    for (int p = 0; p < 4; ++p) {
        const int rr = p * 16 + (t >> 4);
        const int cc = (t & 15) * 4;
        const f32x4 v = *(const f32x4*)(B + (size_t)(r0 + rr) * NN + c0 + cc);
        #pragma unroll
        for (int q = 0; q < 4; ++q) tile[rr][cc + q] = f2bf(v[q]);
    }
    __syncthreads();
    #pragma unroll
    for (int p = 0; p < 2; ++p) {
        const int oc = p * 32 + (t >> 3);
        const int r8 = (t & 7) * 8;
        u16x8 o;
        #pragma unroll
        for (int j = 0; j < 8; ++j) o[j] = tile[r8 + j][oc];
        *(u16x8*)(Bt + (size_t)(c0 + oc) * NN + r0 + r8) = o;
    }
}

// ---------------- triangular bf16 GEMM: C(lower) = A @ B, A=[M][K], Bt=[N][K] ----------------
__global__ __launch_bounds__(256) void tri_gemm(const unsigned short* __restrict__ A,
                                                const unsigned short* __restrict__ Bt,
                                                float* __restrict__ C) {
    const int bi = gridDim.y - 1 - blockIdx.y;   // long-K blocks dispatch first
    const int bj = blockIdx.x;
    if (bj > bi) return;                          // upper tiles: memset already zeroed

    __shared__ alignas(16) unsigned short sA[BM * BK];   // 16 KB, swizzled slots
    __shared__ alignas(16) unsigned short sB[BM * BK];   // 16 KB

    const int t    = threadIdx.x;
    const int wave = t >> 6;
    const int lane = t & 63;
    const int wr   = wave >> 1, wc = wave & 1;   // 2x2 waves -> 64x64 out each
    const int lr   = lane & 15, lk = lane >> 4;

    f32x4 acc[4][4] = {};

    const size_t arow0 = (size_t)bi * BM;
    const size_t brow0 = (size_t)bj * BM;
    const int    k00   = bj * BM;
    const int    ksteps = (bi - bj + 1) * (BM / BK);

    for (int step = 0; step < ksteps; ++step) {
        const int k0 = k00 + step * BK;
        __syncthreads();   // prior compute done before overwriting LDS
        #pragma unroll
        for (int i = 0; i < 4; ++i) {
            const int off = i * 4096 + t * 16;              // linear LDS byte offset
            const int r   = off >> 7;                       // tile row (128B rows)
            const int ss  = ((off >> 4) & 7) ^ (r & 7);     // inverse-swizzled source slot
            const unsigned short* ga = A  + (arow0 + r) * NN + k0 + ss * 8;
            const unsigned short* gb = Bt + (brow0 + r) * NN + k0 + ss * 8;
            char* la = (char*)sA + i * 4096 + wave * 1024;  // wave-uniform dest
            char* lb = (char*)sB + i * 4096 + wave * 1024;
            __builtin_amdgcn_global_load_lds(
                (const __attribute__((address_space(1))) void*)ga,
                (__attribute__((address_space(3))) void*)la, 16, 0, 0);
            __builtin_amdgcn_global_load_lds(
                (const __attribute__((address_space(1))) void*)gb,
                (__attribute__((address_space(3))) void*)lb, 16, 0, 0);
        }
        __syncthreads();   // drains vmcnt(0): staged data visible
        #pragma unroll
        for (int kk = 0; kk < 2; ++kk) {
            bf16x8 af[4], bfr[4];
            #pragma unroll
            for (int m = 0; m < 4; ++m) {
                const int r = wr * 64 + m * 16 + lr;
                const int s = (kk * 4 + lk) ^ (r & 7);      // swizzled read
                af[m] = *(const bf16x8*)((const char*)sA + r * 128 + s * 16);
            }
            #pragma unroll
            for (int n = 0; n < 4; ++n) {
                const int r = wc * 64 + n * 16 + lr;
                const int s = (kk * 4 + lk) ^ (r & 7);
                bfr[n] = *(const bf16x8*)((const char*)sB + r * 128 + s * 16);
            }
            #pragma unroll
            for (int m = 0; m < 4; ++m)
                #pragma unroll
                for (int n = 0; n < 4; ++n)
                    acc[m][n] = __builtin_amdgcn_mfma_f32_16x16x32_bf16(
                        af[m], bfr[n], acc[m][n], 0, 0, 0);
        }
    }

    // epilogue: D col = lane&15, row = (lane>>4)*4 + reg
    const size_t crow0 = (size_t)bi * BM + wr * 64;
    const int    ccol0 = bj * BM + wc * 64;
    #pragma unroll
    for (int m = 0; m < 4; ++m)
        #pragma unroll
        for (int n = 0; n < 4; ++n)
            #pragma unroll
            for (int q = 0; q < 4; ++q) {
                const size_t row = crow0 + m * 16 + lk * 4 + q;
                const int    col = ccol0 + n * 16 + lr;
                C[row * NN + col] = acc[m][n][q];
            }
}

extern "C" void kernel_launch(void* const* d_in, const int* in_sizes, int n_in,
                              void* d_out, int out_size, void* d_ws, size_t ws_size,
                              hipStream_t stream) {
    const float* A = (const float*)d_in[0];
    const float* B = (const float*)d_in[1];
    float*       C = (float*)d_out;

    unsigned short* Ab  = (unsigned short*)d_ws;                 // 128 MB
    unsigned short* Btw = Ab + (size_t)NN * NN;                  // 128 MB

    // upper triangle must be zero (d_out poisoned 0xAA before every launch)
    hipMemsetAsync(d_out, 0, (size_t)NN * NN * sizeof(float), stream);

    conv_a_kernel<<<2048, 256, 0, stream>>>(A, Ab);
    conv_trans_b<<<dim3(128, 128), 256, 0, stream>>>(B, Btw);
    tri_gemm<<<dim3(64, 64), 256, 0, stream>>>(Ab, Btw, C);
}

// Round 3
// 924.899 us; speedup vs baseline: 1.1314x; 1.1314x over previous
//
#include <hip/hip_runtime.h>
#include <hip/hip_bf16.h>
#include <math.h>

#define NN 8192
#define BM 128
#define BK 64

typedef __attribute__((ext_vector_type(8))) short          bf16x8;
typedef __attribute__((ext_vector_type(8))) unsigned short u16x8;
typedef __attribute__((ext_vector_type(4))) float          f32x4;

__device__ __forceinline__ unsigned short f2bf(float f) {
    unsigned int u = __builtin_bit_cast(unsigned int, f);
    u += 0x7fffu + ((u >> 16) & 1u);   // RNE; exact zeros stay zero
    return (unsigned short)(u >> 16);
}

// ---------------------------------------------------------------------------
// Fused triangular converter. One block per lower-triangle 128x128 tile
// (ti >= tj). Converts A tile fp32->bf16 in-layout, and transpose-converts
// B tile (k in ti-block, n in tj-block) -> Bt[n][k] via padded LDS.
// Upper tiles of Ab/Bt are never written — the GEMM never reads them.
// ---------------------------------------------------------------------------
__global__ __launch_bounds__(256) void conv_fused(const float* __restrict__ A,
                                                  const float* __restrict__ B,
                                                  unsigned short* __restrict__ Ab,
                                                  unsigned short* __restrict__ Bt) {
    __shared__ unsigned short ldsB[128][130];   // pad->row stride 65 banks (odd)

    const int q  = blockIdx.x;
    int ti = (int)((sqrtf(8.0f * (float)q + 1.0f) - 1.0f) * 0.5f);
    while ((ti + 1) * (ti + 2) / 2 <= q) ++ti;  // guard fp rounding
    while (ti * (ti + 1) / 2 > q) --ti;
    const int tj = q - ti * (ti + 1) / 2;       // tj <= ti

    const int t  = threadIdx.x;
    const int rr0 = t >> 4;          // 0..15
    const int cc  = (t & 15) * 8;    // 0..120

    // ---- A tile: straight convert (input upper-of-diagonal is already 0) ----
    {
        const size_t r0 = (size_t)ti * 128, c0 = (size_t)tj * 128;
        #pragma unroll
        for (int p = 0; p < 8; ++p) {
            const int rr = p * 16 + rr0;
            const float* src = A + (r0 + rr) * NN + c0 + cc;
            const f32x4 v0 = *(const f32x4*)src;
            const f32x4 v1 = *(const f32x4*)(src + 4);
            u16x8 o;
            o[0]=f2bf(v0[0]); o[1]=f2bf(v0[1]); o[2]=f2bf(v0[2]); o[3]=f2bf(v0[3]);
            o[4]=f2bf(v1[0]); o[5]=f2bf(v1[1]); o[6]=f2bf(v1[2]); o[7]=f2bf(v1[3]);
            *(u16x8*)(Ab + (r0 + rr) * NN + c0 + cc) = o;
        }
    }

    // ---- B tile: read B[k0+.., n0+..], transpose through LDS, write Bt ----
    {
        const size_t k0 = (size_t)ti * 128, n0 = (size_t)tj * 128;
        #pragma unroll
        for (int p = 0; p < 8; ++p) {
            const int rr = p * 16 + rr0;
            const float* src = B + (k0 + rr) * NN + n0 + cc;
            const f32x4 v0 = *(const f32x4*)src;
            const f32x4 v1 = *(const f32x4*)(src + 4);
            #pragma unroll
            for (int j = 0; j < 4; ++j) {
                ldsB[rr][cc + j]     = f2bf(v0[j]);
                ldsB[rr][cc + 4 + j] = f2bf(v1[j]);
            }
        }
        __syncthreads();
        #pragma unroll
        for (int p = 0; p < 8; ++p) {
            const int nr = p * 16 + rr0;    // output row (n)
            u16x8 o;
            #pragma unroll
            for (int j = 0; j < 8; ++j) o[j] = ldsB[cc + j][nr];
            *(u16x8*)(Bt + (n0 + nr) * NN + k0 + cc) = o;
        }
    }
}

// ---------------- triangular bf16 GEMM: C(lower) = A @ B, A=[M][K], Bt=[N][K] ----------------
__global__ __launch_bounds__(256) void tri_gemm(const unsigned short* __restrict__ A,
                                                const unsigned short* __restrict__ Bt,
                                                float* __restrict__ C) {
    const int bi = gridDim.y - 1 - blockIdx.y;   // long-K rows dispatch first (LPT-ish)
    const int bj = blockIdx.x;
    const int t  = threadIdx.x;

    if (bj > bi) {
        // upper-triangle tile: write zeros (replaces the global memset pass)
        const f32x4 z = {0.f, 0.f, 0.f, 0.f};
        const size_t r0 = (size_t)bi * BM;
        const int    c0 = bj * BM;
        #pragma unroll
        for (int p = 0; p < 16; ++p) {
            const int rr = p * 8 + (t >> 5);
            const int cc = (t & 31) * 4;
            *(f32x4*)(C + (r0 + rr) * NN + c0 + cc) = z;
        }
        return;
    }

    __shared__ alignas(16) unsigned short sA[BM * BK];   // 16 KB, swizzled slots
    __shared__ alignas(16) unsigned short sB[BM * BK];   // 16 KB

    const int wave = t >> 6;
    const int lane = t & 63;
    const int wr   = wave >> 1, wc = wave & 1;   // 2x2 waves -> 64x64 out each
    const int lr   = lane & 15, lk = lane >> 4;

    f32x4 acc[4][4] = {};

    const size_t arow0 = (size_t)bi * BM;
    const size_t brow0 = (size_t)bj * BM;
    const int    k00   = bj * BM;
    const int    ksteps = (bi - bj + 1) * (BM / BK);

    for (int step = 0; step < ksteps; ++step) {
        const int k0 = k00 + step * BK;
        __syncthreads();   // prior compute done before overwriting LDS
        #pragma unroll
        for (int i = 0; i < 4; ++i) {
            const int off = i * 4096 + t * 16;              // linear LDS byte offset
            const int r   = off >> 7;                       // tile row (128B rows)
            const int ss  = ((off >> 4) & 7) ^ (r & 7);     // inverse-swizzled source slot
            const unsigned short* ga = A  + (arow0 + r) * NN + k0 + ss * 8;
            const unsigned short* gb = Bt + (brow0 + r) * NN + k0 + ss * 8;
            char* la = (char*)sA + i * 4096 + wave * 1024;  // wave-uniform dest
            char* lb = (char*)sB + i * 4096 + wave * 1024;
            __builtin_amdgcn_global_load_lds(
                (const __attribute__((address_space(1))) void*)ga,
                (__attribute__((address_space(3))) void*)la, 16, 0, 0);
            __builtin_amdgcn_global_load_lds(
                (const __attribute__((address_space(1))) void*)gb,
                (__attribute__((address_space(3))) void*)lb, 16, 0, 0);
        }
        __syncthreads();   // drains vmcnt(0): staged data visible
        #pragma unroll
        for (int kk = 0; kk < 2; ++kk) {
            bf16x8 af[4], bfr[4];
            #pragma unroll
            for (int m = 0; m < 4; ++m) {
                const int r = wr * 64 + m * 16 + lr;
                const int s = (kk * 4 + lk) ^ (r & 7);      // swizzled read
                af[m] = *(const bf16x8*)((const char*)sA + r * 128 + s * 16);
            }
            #pragma unroll
            for (int n = 0; n < 4; ++n) {
                const int r = wc * 64 + n * 16 + lr;
                const int s = (kk * 4 + lk) ^ (r & 7);
                bfr[n] = *(const bf16x8*)((const char*)sB + r * 128 + s * 16);
            }
            #pragma unroll
            for (int m = 0; m < 4; ++m)
                #pragma unroll
                for (int n = 0; n < 4; ++n)
                    acc[m][n] = __builtin_amdgcn_mfma_f32_16x16x32_bf16(
                        af[m], bfr[n], acc[m][n], 0, 0, 0);
        }
    }

    // epilogue: D col = lane&15, row = (lane>>4)*4 + reg
    const size_t crow0 = (size_t)bi * BM + wr * 64;
    const int    ccol0 = bj * BM + wc * 64;
    #pragma unroll
    for (int m = 0; m < 4; ++m)
        #pragma unroll
        for (int n = 0; n < 4; ++n)
            #pragma unroll
            for (int q2 = 0; q2 < 4; ++q2) {
                const size_t row = crow0 + m * 16 + lk * 4 + q2;
                const int    col = ccol0 + n * 16 + lr;
                C[row * NN + col] = acc[m][n][q2];
            }
}

extern "C" void kernel_launch(void* const* d_in, const int* in_sizes, int n_in,
                              void* d_out, int out_size, void* d_ws, size_t ws_size,
                              hipStream_t stream) {
    const float* A = (const float*)d_in[0];
    const float* B = (const float*)d_in[1];
    float*       C = (float*)d_out;

    unsigned short* Ab  = (unsigned short*)d_ws;                 // 128 MB
    unsigned short* Btw = Ab + (size_t)NN * NN;                  // 128 MB

    const int ntiles = (NN / 128) * (NN / 128 + 1) / 2;          // 2080 lower tiles
    conv_fused<<<ntiles, 256, 0, stream>>>(A, B, Ab, Btw);
    tri_gemm<<<dim3(64, 64), 256, 0, stream>>>(Ab, Btw, C);
}